// Round 1
// 717.752 us; speedup vs baseline: 1.0048x; 1.0048x over previous
//
#include <hip/hip_runtime.h>
#include <hip/hip_bf16.h>
#include <cstdint>
#include <cstddef>

#define NEXP  8
#define NTOK  4096
#define HID   1024
#define INTER 3584
#define CAP   2048   // per-expert cap == reference jnp.nonzero(size=seq_len)

#define BM  128
#define BN  128
#define BK  32

typedef __attribute__((ext_vector_type(4))) float floatx4;
typedef __attribute__((ext_vector_type(8))) short shortx8;
typedef unsigned short u16;

__device__ __forceinline__ u16 f2bf(float f) {
    union { float f; unsigned u; } v; v.f = f;
    unsigned r = v.u + 0x7fffu + ((v.u >> 16) & 1u);   // RNE
    return (u16)(r >> 16);
}

__device__ __forceinline__ shortx8 pack8(const float* v) {
    shortx8 r;
#pragma unroll
    for (int i = 0; i < 8; ++i) r[i] = (short)f2bf(v[i]);
    return r;
}

// HW packed fp32->bf16 convert: lo = bf16(a), hi = bf16(b), RNE.
__device__ __forceinline__ unsigned cvt_pk_bf16(float a, float b) {
    unsigned r;
    asm("v_cvt_pk_bf16_f32 %0, %1, %2" : "=v"(r) : "v"(a), "v"(b));
    return r;
}

// async global->LDS, 16B per lane. LDS dest must be wave-uniform base + lane*16.
__device__ __forceinline__ void async_ld16(const void* g, void* l) {
    __builtin_amdgcn_global_load_lds(
        (const __attribute__((address_space(1))) unsigned int*)g,
        (__attribute__((address_space(3))) unsigned int*)l, 16, 0, 0);
}

// ---------------- routing: per-expert token lists ----------------
__global__ void route_kernel(const int* __restrict__ mask, const float* __restrict__ rw,
                             int* __restrict__ cnt, int* __restrict__ list,
                             float* __restrict__ wgt) {
    int t = blockIdx.x * blockDim.x + threadIdx.x;
    if (t >= NTOK) return;
#pragma unroll
    for (int e = 0; e < NEXP; ++e) {
#pragma unroll
        for (int k = 0; k < 2; ++k) {
            if (mask[(e * 2 + k) * NTOK + t] != 0) {
                int pos = atomicAdd(&cnt[e], 1);
                if (pos < CAP) {
                    list[e * CAP + pos] = t;
                    wgt[e * CAP + pos] = rw[t * 2 + k];
                }
            }
        }
    }
}

// ---------------- X: fp32 -> bf16, same layout ----------------
__global__ void xcvt_kernel(const float* __restrict__ X, u16* __restrict__ Xb) {
    const int i = (blockIdx.x * 256 + threadIdx.x) * 8;
    float4 a = *(const float4*)&X[i];
    float4 b = *(const float4*)&X[i + 4];
    float v[8] = {a.x, a.y, a.z, a.w, b.x, b.y, b.z, b.w};
    *(shortx8*)&Xb[i] = pack8(v);
}

// ---------------- W: [e][K][N] fp32 -> [e][N][K] bf16 (transpose+convert) ----------------
// 64x64 tile per block, 256 threads.
// Phase 1: each thread loads a 4(k) x 4(n) fp32 patch (4x float4, coalesced),
//          packs along k with v_cvt_pk_bf16_f32 (transpose happens inside the pack),
//          writes 4x ds_write_b64 into padded [64][34]-u32 LDS (2-way banks = free).
// Phase 2: each thread reads 4x ds_read_b64 of one dst row and stores 2x16B coalesced.
__global__ void transpose_cvt_kernel(const float* __restrict__ src, u16* __restrict__ dst,
                                     int K, int N) {
    const int e = blockIdx.z;
    src += (size_t)e * K * N;
    dst += (size_t)e * K * N;
    const int n0 = blockIdx.x * 64;
    const int k0 = blockIdx.y * 64;
    __shared__ unsigned ldsT[64 * 34];   // [n][34] u32: u16 col c of row n == k0 + c; +2 u32 pad
    const int tid = threadIdx.x;

    {
        const int np = tid & 15;             // n-patch: cols n0 + np*4 .. +3
        const int kp = tid >> 4;             // 0..15:  rows k0 + kp*4 .. +3
        const float* sp = src + (size_t)(k0 + kp * 4) * N + n0 + np * 4;
        float4 r0 = *(const float4*)sp;
        float4 r1 = *(const float4*)(sp + (size_t)N);
        float4 r2 = *(const float4*)(sp + 2 * (size_t)N);
        float4 r3 = *(const float4*)(sp + 3 * (size_t)N);
        const float c0[4] = {r0.x, r0.y, r0.z, r0.w};
        const float c1[4] = {r1.x, r1.y, r1.z, r1.w};
        const float c2[4] = {r2.x, r2.y, r2.z, r2.w};
        const float c3[4] = {r3.x, r3.y, r3.z, r3.w};
#pragma unroll
        for (int j = 0; j < 4; ++j) {
            const int n = np * 4 + j;
            uint2 w;
            w.x = cvt_pk_bf16(c0[j], c1[j]);   // (k+0, k+1) of dst row n
            w.y = cvt_pk_bf16(c2[j], c3[j]);   // (k+2, k+3)
            *(uint2*)&ldsT[n * 34 + kp * 2] = w;
        }
    }
    __syncthreads();
    {
        const int n = tid >> 2;              // 0..63
        const int q = tid & 3;               // 16-k chunk
        unsigned r[8];
#pragma unroll
        for (int i = 0; i < 4; ++i) {
            uint2 v = *(const uint2*)&ldsT[n * 34 + (q * 4 + i) * 2];
            r[i * 2] = v.x; r[i * 2 + 1] = v.y;
        }
        u16* dp = dst + (size_t)(n0 + n) * K + k0 + q * 16;
        *(uint4*)&dp[0] = *(const uint4*)&r[0];
        *(uint4*)&dp[8] = *(const uint4*)&r[4];
    }
}

// ---------------- GEMM1: H = silu(X w1) * (X w3) * rw, bf16 out ----------------
// A: gathered token rows of Xb [tok][HID]; B: W1b/W3b [e][INTER][HID] (n-major).
__global__ __launch_bounds__(256, 2)
void gemm1_kernel(const u16* __restrict__ Xb, const u16* __restrict__ W1b,
                  const u16* __restrict__ W3b, const int* __restrict__ cnt,
                  const int* __restrict__ list, const float* __restrict__ wgt,
                  u16* __restrict__ H) {
    const int e  = blockIdx.z;
    const int ce = min(cnt[e], CAP);
    const int m0 = blockIdx.y * BM;
    if (m0 >= ce) return;
    const int n0 = blockIdx.x * BN;

    __shared__ u16 lA [BM * BK];   // [row][k] 32 u16/row = 64B, no pad (global_load_lds)
    __shared__ u16 lB1[BN * BK];
    __shared__ u16 lB3[BN * BK];

    const int tid  = threadIdx.x;
    const int lane = tid & 63;
    const int wave = tid >> 6;

    // staging map: chunk c in {0,1}: lds u16-off = wave*1024 + c*512 + lane*8
    //   -> row = wave*32 + c*16 + lane/4, kcol = (lane&3)*8
    const int srow0 = wave * 32 + (lane >> 2);
    const int srow1 = srow0 + 16;
    const int scol  = (lane & 3) * 8;
    const int lo0 = wave * 1024 + lane * 8;
    const int lo1 = lo0 + 512;

    const int t0 = list[e * CAP + min(m0 + srow0, ce - 1)];
    const int t1 = list[e * CAP + min(m0 + srow1, ce - 1)];
    const u16* ap0  = Xb + (size_t)t0 * HID + scol;
    const u16* ap1  = Xb + (size_t)t1 * HID + scol;
    const u16* b1p0 = W1b + ((size_t)e * INTER + n0 + srow0) * HID + scol;
    const u16* b1p1 = b1p0 + (size_t)16 * HID;
    const u16* b3p0 = W3b + ((size_t)e * INTER + n0 + srow0) * HID + scol;
    const u16* b3p1 = b3p0 + (size_t)16 * HID;

    const int fl = lane & 15, fq = lane >> 4;
    const int wm  = (wave >> 1) * 64;
    const int wnn = (wave & 1) * 64;

    floatx4 acc1[4][4], acc3[4][4];
#pragma unroll
    for (int i = 0; i < 4; ++i)
#pragma unroll
        for (int j = 0; j < 4; ++j)
#pragma unroll
            for (int r = 0; r < 4; ++r) { acc1[i][j][r] = 0.f; acc3[i][j][r] = 0.f; }

    for (int k0 = 0; k0 < HID; k0 += BK) {
        __syncthreads();
        async_ld16(ap0  + k0, &lA [lo0]);
        async_ld16(ap1  + k0, &lA [lo1]);
        async_ld16(b1p0 + k0, &lB1[lo0]);
        async_ld16(b1p1 + k0, &lB1[lo1]);
        async_ld16(b3p0 + k0, &lB3[lo0]);
        async_ld16(b3p1 + k0, &lB3[lo1]);
        __syncthreads();

        shortx8 af[4], b1f[4], b3f[4];
#pragma unroll
        for (int i = 0; i < 4; ++i)
            af[i] = *(const shortx8*)&lA[(wm + i * 16 + fl) * BK + fq * 8];
#pragma unroll
        for (int j = 0; j < 4; ++j) {
            b1f[j] = *(const shortx8*)&lB1[(wnn + j * 16 + fl) * BK + fq * 8];
            b3f[j] = *(const shortx8*)&lB3[(wnn + j * 16 + fl) * BK + fq * 8];
        }
#pragma unroll
        for (int i = 0; i < 4; ++i)
#pragma unroll
            for (int j = 0; j < 4; ++j) {
                acc1[i][j] = __builtin_amdgcn_mfma_f32_16x16x32_bf16(af[i], b1f[j], acc1[i][j], 0, 0, 0);
                acc3[i][j] = __builtin_amdgcn_mfma_f32_16x16x32_bf16(af[i], b3f[j], acc3[i][j], 0, 0, 0);
            }
    }

    // epilogue: silu(a1)*a3 * rw -> bf16 H
#pragma unroll
    for (int i = 0; i < 4; ++i) {
        const int rowb = m0 + wm + i * 16 + fq * 4;
#pragma unroll
        for (int r = 0; r < 4; ++r) {
            const int row = rowb + r;
            const bool valid = row < ce;
            const float rwv = valid ? wgt[e * CAP + row] : 0.f;
            u16* hp = H + (size_t)(e * CAP + (valid ? row : 0)) * INTER;
#pragma unroll
            for (int j = 0; j < 4; ++j) {
                const int col = n0 + wnn + j * 16 + fl;
                float h1 = acc1[i][j][r];
                float h3 = acc3[i][j][r];
                float sv = h1 / (1.f + __expf(-h1)) * h3 * rwv;
                if (valid) hp[col] = f2bf(sv);
            }
        }
    }
}

// ---------------- GEMM2: out[tok] += H w2 ----------------
// A: H rows [e*CAP+row][INTER] bf16; B: W2b [e][HID][INTER] (n-major).
__global__ __launch_bounds__(256, 2)
void gemm2_kernel(const u16* __restrict__ H, const u16* __restrict__ W2b,
                  const int* __restrict__ cnt, const int* __restrict__ list,
                  float* __restrict__ out) {
    const int e  = blockIdx.z;
    const int ce = min(cnt[e], CAP);
    const int m0 = blockIdx.y * BM;
    if (m0 >= ce) return;
    const int n0 = blockIdx.x * BN;

    __shared__ u16 lA[BM * BK];
    __shared__ u16 lB[BN * BK];

    const int tid  = threadIdx.x;
    const int lane = tid & 63;
    const int wave = tid >> 6;

    const int srow0 = wave * 32 + (lane >> 2);
    const int srow1 = srow0 + 16;
    const int scol  = (lane & 3) * 8;
    const int lo0 = wave * 1024 + lane * 8;
    const int lo1 = lo0 + 512;

    const u16* ap0 = H + (size_t)(e * CAP + m0 + srow0) * INTER + scol;  // rows >= ce: poison, masked later
    const u16* ap1 = ap0 + (size_t)16 * INTER;
    const u16* bp0 = W2b + ((size_t)e * HID + n0 + srow0) * INTER + scol;
    const u16* bp1 = bp0 + (size_t)16 * INTER;

    const int fl = lane & 15, fq = lane >> 4;
    const int wm  = (wave >> 1) * 64;
    const int wnn = (wave & 1) * 64;

    floatx4 acc[4][4];
#pragma unroll
    for (int i = 0; i < 4; ++i)
#pragma unroll
        for (int j = 0; j < 4; ++j)
#pragma unroll
            for (int r = 0; r < 4; ++r) acc[i][j][r] = 0.f;

    for (int k0 = 0; k0 < INTER; k0 += BK) {
        __syncthreads();
        async_ld16(ap0 + k0, &lA[lo0]);
        async_ld16(ap1 + k0, &lA[lo1]);
        async_ld16(bp0 + k0, &lB[lo0]);
        async_ld16(bp1 + k0, &lB[lo1]);
        __syncthreads();

        shortx8 af[4], bf[4];
#pragma unroll
        for (int i = 0; i < 4; ++i)
            af[i] = *(const shortx8*)&lA[(wm + i * 16 + fl) * BK + fq * 8];
#pragma unroll
        for (int j = 0; j < 4; ++j)
            bf[j] = *(const shortx8*)&lB[(wnn + j * 16 + fl) * BK + fq * 8];
#pragma unroll
        for (int i = 0; i < 4; ++i)
#pragma unroll
            for (int j = 0; j < 4; ++j)
                acc[i][j] = __builtin_amdgcn_mfma_f32_16x16x32_bf16(af[i], bf[j], acc[i][j], 0, 0, 0);
    }

#pragma unroll
    for (int i = 0; i < 4; ++i) {
        const int rowb = m0 + wm + i * 16 + fq * 4;
#pragma unroll
        for (int r = 0; r < 4; ++r) {
            const int row = rowb + r;
            const bool valid = row < ce;
            const int tok = valid ? list[e * CAP + row] : 0;
            float* op = out + (size_t)tok * HID;
#pragma unroll
            for (int j = 0; j < 4; ++j) {
                const int col = n0 + wnn + j * 16 + fl;
                if (valid) atomicAdd(&op[col], acc[i][j][r]);
            }
        }
    }
}

extern "C" void kernel_launch(void* const* d_in, const int* in_sizes, int n_in,
                              void* d_out, int out_size, void* d_ws, size_t ws_size,
                              hipStream_t stream) {
    const int*   mask = (const int*)  d_in[0];
    const float* X    = (const float*)d_in[1];
    const float* rw   = (const float*)d_in[2];
    const float* w1   = (const float*)d_in[3];
    const float* w2   = (const float*)d_in[4];
    const float* w3   = (const float*)d_in[5];
    float* out = (float*)d_out;

    char* ws = (char*)d_ws;
    size_t off = 0;
    int*   cnt  = (int*)(ws + off);  off += 256;
    int*   list = (int*)(ws + off);  off += (size_t)NEXP * CAP * 4;      // 64 KB
    float* wgt  = (float*)(ws + off); off += (size_t)NEXP * CAP * 4;     // 64 KB
    u16*   Xb   = (u16*)(ws + off);  off += (size_t)NTOK * HID * 2;      // 8 MB
    u16*   W1b  = (u16*)(ws + off);  off += (size_t)NEXP * HID * INTER * 2;  // 56 MB
    u16*   W3b  = (u16*)(ws + off);  off += (size_t)NEXP * HID * INTER * 2;  // 56 MB
    u16*   W2b  = (u16*)(ws + off);  off += (size_t)NEXP * HID * INTER * 2;  // 56 MB
    u16*   H    = (u16*)(ws + off);  off += (size_t)NEXP * CAP * INTER * 2;  // 112 MB

    hipMemsetAsync(cnt, 0, 256, stream);
    hipMemsetAsync(d_out, 0, (size_t)out_size * sizeof(float), stream);

    route_kernel<<<dim3((NTOK + 255) / 256), dim3(256), 0, stream>>>(mask, rw, cnt, list, wgt);
    xcvt_kernel<<<dim3(NTOK * HID / (256 * 8)), dim3(256), 0, stream>>>(X, Xb);
    // w1/w3: [e][HID][INTER] -> [e][INTER][HID]
    transpose_cvt_kernel<<<dim3(INTER / 64, HID / 64, NEXP), dim3(256), 0, stream>>>(w1, W1b, HID, INTER);
    transpose_cvt_kernel<<<dim3(INTER / 64, HID / 64, NEXP), dim3(256), 0, stream>>>(w3, W3b, HID, INTER);
    // w2: [e][INTER][HID] -> [e][HID][INTER]
    transpose_cvt_kernel<<<dim3(HID / 64, INTER / 64, NEXP), dim3(256), 0, stream>>>(w2, W2b, INTER, HID);

    gemm1_kernel<<<dim3(INTER / BN, CAP / BM, NEXP), dim3(256), 0, stream>>>(Xb, W1b, W3b, cnt, list, wgt, H);
    gemm2_kernel<<<dim3(HID / BN, CAP / BM, NEXP), dim3(256), 0, stream>>>(H, W2b, cnt, list, out);
}

// Round 2
// 694.064 us; speedup vs baseline: 1.0391x; 1.0341x over previous
//
#include <hip/hip_runtime.h>
#include <hip/hip_bf16.h>
#include <cstdint>
#include <cstddef>

#define NEXP  8
#define NTOK  4096
#define HID   1024
#define INTER 3584
#define CAP   2048   // per-expert cap == reference jnp.nonzero(size=seq_len)

#define BM  128
#define BN  128
#define BK  32

typedef __attribute__((ext_vector_type(4))) float floatx4;
typedef __attribute__((ext_vector_type(8))) short shortx8;
typedef unsigned short u16;

__device__ __forceinline__ u16 f2bf(float f) {
    union { float f; unsigned u; } v; v.f = f;
    unsigned r = v.u + 0x7fffu + ((v.u >> 16) & 1u);   // RNE
    return (u16)(r >> 16);
}

__device__ __forceinline__ shortx8 pack8(const float* v) {
    shortx8 r;
#pragma unroll
    for (int i = 0; i < 8; ++i) r[i] = (short)f2bf(v[i]);
    return r;
}

// HW packed fp32->bf16 convert: lo = bf16(a), hi = bf16(b), RNE.
__device__ __forceinline__ unsigned cvt_pk_bf16(float a, float b) {
    unsigned r;
    asm("v_cvt_pk_bf16_f32 %0, %1, %2" : "=v"(r) : "v"(a), "v"(b));
    return r;
}

// async global->LDS, 16B per lane. LDS dest must be wave-uniform base + lane*16.
__device__ __forceinline__ void async_ld16(const void* g, void* l) {
    __builtin_amdgcn_global_load_lds(
        (const __attribute__((address_space(1))) unsigned int*)g,
        (__attribute__((address_space(3))) unsigned int*)l, 16, 0, 0);
}

__device__ __forceinline__ void wait_vm0_barrier() {
    asm volatile("s_waitcnt vmcnt(0)" ::: "memory");
    __builtin_amdgcn_s_barrier();
    __builtin_amdgcn_sched_barrier(0);
}

// ---------------- routing: per-expert token lists ----------------
__global__ void route_kernel(const int* __restrict__ mask, const float* __restrict__ rw,
                             int* __restrict__ cnt, int* __restrict__ list,
                             float* __restrict__ wgt) {
    int t = blockIdx.x * blockDim.x + threadIdx.x;
    if (t >= NTOK) return;
#pragma unroll
    for (int e = 0; e < NEXP; ++e) {
#pragma unroll
        for (int k = 0; k < 2; ++k) {
            if (mask[(e * 2 + k) * NTOK + t] != 0) {
                int pos = atomicAdd(&cnt[e], 1);
                if (pos < CAP) {
                    list[e * CAP + pos] = t;
                    wgt[e * CAP + pos] = rw[t * 2 + k];
                }
            }
        }
    }
}

// ---------------- X: fp32 -> bf16, same layout ----------------
__global__ void xcvt_kernel(const float* __restrict__ X, u16* __restrict__ Xb) {
    const int i = (blockIdx.x * 256 + threadIdx.x) * 8;
    float4 a = *(const float4*)&X[i];
    float4 b = *(const float4*)&X[i + 4];
    float v[8] = {a.x, a.y, a.z, a.w, b.x, b.y, b.z, b.w};
    *(shortx8*)&Xb[i] = pack8(v);
}

// ---------------- W prep (merged): [e][K][N] fp32 -> [e][N][K] bf16 for w1,w3,w2 ----------------
// One dispatch so the prep cost is visible as a single top-k row in rocprof.
// 64x64 tile per block, 256 threads. grid = (896, NEXP, 3).
__global__ void transpose_cvt_all_kernel(const float* __restrict__ w1,
                                         const float* __restrict__ w2,
                                         const float* __restrict__ w3,
                                         u16* __restrict__ W1b, u16* __restrict__ W2b,
                                         u16* __restrict__ W3b) {
    const int wsel = blockIdx.z;
    const int e    = blockIdx.y;
    const float* src; u16* dst; int K, N, nx;
    if (wsel == 0)      { src = w1; dst = W1b; K = HID;   N = INTER; nx = INTER / 64; }
    else if (wsel == 1) { src = w3; dst = W3b; K = HID;   N = INTER; nx = INTER / 64; }
    else                { src = w2; dst = W2b; K = INTER; N = HID;   nx = HID / 64;   }
    src += (size_t)e * K * N;
    dst += (size_t)e * K * N;
    const int tile = blockIdx.x;
    const int n0 = (tile % nx) * 64;
    const int k0 = (tile / nx) * 64;

    __shared__ unsigned ldsT[64 * 34];   // [n][34] u32: u16 col c of row n == k0 + c; +2 u32 pad
    const int tid = threadIdx.x;
    {
        const int np = tid & 15;             // n-patch: cols n0 + np*4 .. +3
        const int kp = tid >> 4;             // 0..15:  rows k0 + kp*4 .. +3
        const float* sp = src + (size_t)(k0 + kp * 4) * N + n0 + np * 4;
        float4 r0 = *(const float4*)sp;
        float4 r1 = *(const float4*)(sp + (size_t)N);
        float4 r2 = *(const float4*)(sp + 2 * (size_t)N);
        float4 r3 = *(const float4*)(sp + 3 * (size_t)N);
        const float c0[4] = {r0.x, r0.y, r0.z, r0.w};
        const float c1[4] = {r1.x, r1.y, r1.z, r1.w};
        const float c2[4] = {r2.x, r2.y, r2.z, r2.w};
        const float c3[4] = {r3.x, r3.y, r3.z, r3.w};
#pragma unroll
        for (int j = 0; j < 4; ++j) {
            const int n = np * 4 + j;
            uint2 w;
            w.x = cvt_pk_bf16(c0[j], c1[j]);   // (k+0, k+1) of dst row n
            w.y = cvt_pk_bf16(c2[j], c3[j]);   // (k+2, k+3)
            *(uint2*)&ldsT[n * 34 + kp * 2] = w;
        }
    }
    __syncthreads();
    {
        const int n = tid >> 2;              // 0..63
        const int q = tid & 3;               // 16-k chunk
        unsigned r[8];
#pragma unroll
        for (int i = 0; i < 4; ++i) {
            uint2 v = *(const uint2*)&ldsT[n * 34 + (q * 4 + i) * 2];
            r[i * 2] = v.x; r[i * 2 + 1] = v.y;
        }
        u16* dp = dst + (size_t)(n0 + n) * K + k0 + q * 16;
        *(uint4*)&dp[0] = *(const uint4*)&r[0];
        *(uint4*)&dp[8] = *(const uint4*)&r[4];
    }
}

// ---------------- GEMM1: H = silu(X w1) * (X w3) * rw, bf16 out ----------------
// A: gathered token rows of Xb [tok][HID]; B: W1b/W3b [e][INTER][HID] (n-major).
// T2 both-sides swizzle: LDS row r holds k-chunk c at slot (c ^ ((r>>1)&3)); staging
// pre-swizzles the global source column (same 64B line -> coalescing unchanged).
// T3-lite: double-buffered LDS, next-tile global_load_lds issued before compute,
// single vmcnt(0)+raw-barrier per K-step (no compiler-inserted full drain).
__global__ __launch_bounds__(256, 2)
void gemm1_kernel(const u16* __restrict__ Xb, const u16* __restrict__ W1b,
                  const u16* __restrict__ W3b, const int* __restrict__ cnt,
                  const int* __restrict__ list, const float* __restrict__ wgt,
                  u16* __restrict__ H) {
    const int e  = blockIdx.z;
    const int ce = min(cnt[e], CAP);
    const int m0 = blockIdx.y * BM;
    if (m0 >= ce) return;
    const int n0 = blockIdx.x * BN;

    __shared__ u16 sm[2 * 3 * BM * BK];   // dbuf x {A,B1,B3}, 48 KB

    const int tid  = threadIdx.x;
    const int lane = tid & 63;
    const int wave = tid >> 6;

    // staging map: chunk c in {0,1}: lds u16-off = wave*1024 + c*512 + lane*8
    //   -> row = wave*32 + c*16 + lane/4, kslot = lane&3
    const int srow0 = wave * 32 + (lane >> 2);
    const int srow1 = srow0 + 16;
    // swizzle: s(row) = (row>>1)&3; same for srow0 and srow1 (+16 preserves (r>>1)&3)
    const int s0   = (srow0 >> 1) & 3;
    const int scol = ((lane & 3) ^ s0) * 8;      // pre-swizzled global k-chunk
    const int lo0 = wave * 1024 + lane * 8;
    const int lo1 = lo0 + 512;

    const int t0 = list[e * CAP + min(m0 + srow0, ce - 1)];
    const int t1 = list[e * CAP + min(m0 + srow1, ce - 1)];
    const u16* ap0  = Xb + (size_t)t0 * HID + scol;
    const u16* ap1  = Xb + (size_t)t1 * HID + scol;
    const u16* b1p0 = W1b + ((size_t)e * INTER + n0 + srow0) * HID + scol;
    const u16* b1p1 = b1p0 + (size_t)16 * HID;
    const u16* b3p0 = W3b + ((size_t)e * INTER + n0 + srow0) * HID + scol;
    const u16* b3p1 = b3p0 + (size_t)16 * HID;

    const int fl = lane & 15, fq = lane >> 4;
    const int fqs = (fq ^ ((fl >> 1) & 3)) * 8;  // swizzled read slot (u16 units)
    const int wm  = (wave >> 1) * 64;
    const int wnn = (wave & 1) * 64;

    auto stage = [&](int b, int kk) {
        u16* base = sm + b * (3 * BM * BK);
        async_ld16(ap0  + kk, base + lo0);
        async_ld16(ap1  + kk, base + lo1);
        async_ld16(b1p0 + kk, base + BM * BK + lo0);
        async_ld16(b1p1 + kk, base + BM * BK + lo1);
        async_ld16(b3p0 + kk, base + 2 * BM * BK + lo0);
        async_ld16(b3p1 + kk, base + 2 * BM * BK + lo1);
    };

    floatx4 acc1[4][4], acc3[4][4];
#pragma unroll
    for (int i = 0; i < 4; ++i)
#pragma unroll
        for (int j = 0; j < 4; ++j)
#pragma unroll
            for (int r = 0; r < 4; ++r) { acc1[i][j][r] = 0.f; acc3[i][j][r] = 0.f; }

    const int NT = HID / BK;   // 32
    stage(0, 0);
    wait_vm0_barrier();

    int cur = 0;
    for (int t = 0; t < NT; ++t) {
        if (t + 1 < NT) stage(cur ^ 1, (t + 1) * BK);

        const u16* bA  = sm + cur * (3 * BM * BK);
        const u16* bB1 = bA + BM * BK;
        const u16* bB3 = bA + 2 * BM * BK;

        shortx8 af[4], b1f[4], b3f[4];
#pragma unroll
        for (int i = 0; i < 4; ++i)
            af[i] = *(const shortx8*)&bA[(wm + i * 16 + fl) * BK + fqs];
#pragma unroll
        for (int j = 0; j < 4; ++j) {
            b1f[j] = *(const shortx8*)&bB1[(wnn + j * 16 + fl) * BK + fqs];
            b3f[j] = *(const shortx8*)&bB3[(wnn + j * 16 + fl) * BK + fqs];
        }
#pragma unroll
        for (int i = 0; i < 4; ++i)
#pragma unroll
            for (int j = 0; j < 4; ++j) {
                acc1[i][j] = __builtin_amdgcn_mfma_f32_16x16x32_bf16(af[i], b1f[j], acc1[i][j], 0, 0, 0);
                acc3[i][j] = __builtin_amdgcn_mfma_f32_16x16x32_bf16(af[i], b3f[j], acc3[i][j], 0, 0, 0);
            }

        wait_vm0_barrier();
        cur ^= 1;
    }

    // epilogue: silu(a1)*a3 * rw -> bf16 H
#pragma unroll
    for (int i = 0; i < 4; ++i) {
        const int rowb = m0 + wm + i * 16 + fq * 4;
#pragma unroll
        for (int r = 0; r < 4; ++r) {
            const int row = rowb + r;
            const bool valid = row < ce;
            const float rwv = valid ? wgt[e * CAP + row] : 0.f;
            u16* hp = H + (size_t)(e * CAP + (valid ? row : 0)) * INTER;
#pragma unroll
            for (int j = 0; j < 4; ++j) {
                const int col = n0 + wnn + j * 16 + fl;
                float h1 = acc1[i][j][r];
                float h3 = acc3[i][j][r];
                float sv = h1 / (1.f + __expf(-h1)) * h3 * rwv;
                if (valid) hp[col] = f2bf(sv);
            }
        }
    }
}

// ---------------- GEMM2: out[tok] += H w2 ----------------
// A: H rows [e*CAP+row][INTER] bf16; B: W2b [e][HID][INTER] (n-major).
__global__ __launch_bounds__(256, 2)
void gemm2_kernel(const u16* __restrict__ H, const u16* __restrict__ W2b,
                  const int* __restrict__ cnt, const int* __restrict__ list,
                  float* __restrict__ out) {
    const int e  = blockIdx.z;
    const int ce = min(cnt[e], CAP);
    const int m0 = blockIdx.y * BM;
    if (m0 >= ce) return;
    const int n0 = blockIdx.x * BN;

    __shared__ u16 sm[2 * 2 * BM * BK];   // dbuf x {A,B}, 32 KB

    const int tid  = threadIdx.x;
    const int lane = tid & 63;
    const int wave = tid >> 6;

    const int srow0 = wave * 32 + (lane >> 2);
    const int s0   = (srow0 >> 1) & 3;
    const int scol = ((lane & 3) ^ s0) * 8;
    const int lo0 = wave * 1024 + lane * 8;
    const int lo1 = lo0 + 512;

    const u16* ap0 = H + (size_t)(e * CAP + m0 + srow0) * INTER + scol;  // rows >= ce: poison, masked later
    const u16* ap1 = ap0 + (size_t)16 * INTER;
    const u16* bp0 = W2b + ((size_t)e * HID + n0 + srow0) * INTER + scol;
    const u16* bp1 = bp0 + (size_t)16 * INTER;

    const int fl = lane & 15, fq = lane >> 4;
    const int fqs = (fq ^ ((fl >> 1) & 3)) * 8;
    const int wm  = (wave >> 1) * 64;
    const int wnn = (wave & 1) * 64;

    auto stage = [&](int b, int kk) {
        u16* base = sm + b * (2 * BM * BK);
        async_ld16(ap0 + kk, base + lo0);
        async_ld16(ap1 + kk, base + lo1);
        async_ld16(bp0 + kk, base + BM * BK + lo0);
        async_ld16(bp1 + kk, base + BM * BK + lo1);
    };

    floatx4 acc[4][4];
#pragma unroll
    for (int i = 0; i < 4; ++i)
#pragma unroll
        for (int j = 0; j < 4; ++j)
#pragma unroll
            for (int r = 0; r < 4; ++r) acc[i][j][r] = 0.f;

    const int NT = INTER / BK;   // 112
    stage(0, 0);
    wait_vm0_barrier();

    int cur = 0;
    for (int t = 0; t < NT; ++t) {
        if (t + 1 < NT) stage(cur ^ 1, (t + 1) * BK);

        const u16* bA = sm + cur * (2 * BM * BK);
        const u16* bB = bA + BM * BK;

        shortx8 af[4], bf[4];
#pragma unroll
        for (int i = 0; i < 4; ++i)
            af[i] = *(const shortx8*)&bA[(wm + i * 16 + fl) * BK + fqs];
#pragma unroll
        for (int j = 0; j < 4; ++j)
            bf[j] = *(const shortx8*)&bB[(wnn + j * 16 + fl) * BK + fqs];
#pragma unroll
        for (int i = 0; i < 4; ++i)
#pragma unroll
            for (int j = 0; j < 4; ++j)
                acc[i][j] = __builtin_amdgcn_mfma_f32_16x16x32_bf16(af[i], bf[j], acc[i][j], 0, 0, 0);

        wait_vm0_barrier();
        cur ^= 1;
    }

#pragma unroll
    for (int i = 0; i < 4; ++i) {
        const int rowb = m0 + wm + i * 16 + fq * 4;
#pragma unroll
        for (int r = 0; r < 4; ++r) {
            const int row = rowb + r;
            const bool valid = row < ce;
            const int tok = valid ? list[e * CAP + row] : 0;
            float* op = out + (size_t)tok * HID;
#pragma unroll
            for (int j = 0; j < 4; ++j) {
                const int col = n0 + wnn + j * 16 + fl;
                if (valid) atomicAdd(&op[col], acc[i][j][r]);
            }
        }
    }
}

extern "C" void kernel_launch(void* const* d_in, const int* in_sizes, int n_in,
                              void* d_out, int out_size, void* d_ws, size_t ws_size,
                              hipStream_t stream) {
    const int*   mask = (const int*)  d_in[0];
    const float* X    = (const float*)d_in[1];
    const float* rw   = (const float*)d_in[2];
    const float* w1   = (const float*)d_in[3];
    const float* w2   = (const float*)d_in[4];
    const float* w3   = (const float*)d_in[5];
    float* out = (float*)d_out;

    char* ws = (char*)d_ws;
    size_t off = 0;
    int*   cnt  = (int*)(ws + off);  off += 256;
    int*   list = (int*)(ws + off);  off += (size_t)NEXP * CAP * 4;      // 64 KB
    float* wgt  = (float*)(ws + off); off += (size_t)NEXP * CAP * 4;     // 64 KB
    u16*   Xb   = (u16*)(ws + off);  off += (size_t)NTOK * HID * 2;      // 8 MB
    u16*   W1b  = (u16*)(ws + off);  off += (size_t)NEXP * HID * INTER * 2;  // 56 MB
    u16*   W3b  = (u16*)(ws + off);  off += (size_t)NEXP * HID * INTER * 2;  // 56 MB
    u16*   W2b  = (u16*)(ws + off);  off += (size_t)NEXP * HID * INTER * 2;  // 56 MB
    u16*   H    = (u16*)(ws + off);  off += (size_t)NEXP * CAP * INTER * 2;  // 112 MB

    hipMemsetAsync(cnt, 0, 256, stream);
    hipMemsetAsync(d_out, 0, (size_t)out_size * sizeof(float), stream);

    route_kernel<<<dim3((NTOK + 255) / 256), dim3(256), 0, stream>>>(mask, rw, cnt, list, wgt);
    xcvt_kernel<<<dim3(NTOK * HID / (256 * 8)), dim3(256), 0, stream>>>(X, Xb);
    // all three weights in one dispatch: w1/w3 [e][HID][INTER]->[e][INTER][HID], w2 [e][INTER][HID]->[e][HID][INTER]
    transpose_cvt_all_kernel<<<dim3((HID / 64) * (INTER / 64), NEXP, 3), dim3(256), 0, stream>>>(
        w1, w2, w3, W1b, W2b, W3b);

    gemm1_kernel<<<dim3(INTER / BN, CAP / BM, NEXP), dim3(256), 0, stream>>>(Xb, W1b, W3b, cnt, list, wgt, H);
    gemm2_kernel<<<dim3(HID / BN, CAP / BM, NEXP), dim3(256), 0, stream>>>(H, W2b, cnt, list, out);
}

// Round 3
// 661.068 us; speedup vs baseline: 1.0909x; 1.0499x over previous
//
#include <hip/hip_runtime.h>
#include <hip/hip_bf16.h>
#include <cstdint>
#include <cstddef>

#define NEXP  8
#define NTOK  4096
#define HID   1024
#define INTER 3584
#define CAP   2048   // per-expert cap == reference jnp.nonzero(size=seq_len)

#define BM  128
#define BN  128
#define BK  32

typedef __attribute__((ext_vector_type(4))) float floatx4;
typedef __attribute__((ext_vector_type(8))) short shortx8;
typedef unsigned short u16;

#define WAITVM(N) asm volatile("s_waitcnt vmcnt(" #N ")" ::: "memory")

__device__ __forceinline__ u16 f2bf(float f) {
    union { float f; unsigned u; } v; v.f = f;
    unsigned r = v.u + 0x7fffu + ((v.u >> 16) & 1u);   // RNE
    return (u16)(r >> 16);
}

__device__ __forceinline__ shortx8 pack8(const float* v) {
    shortx8 r;
#pragma unroll
    for (int i = 0; i < 8; ++i) r[i] = (short)f2bf(v[i]);
    return r;
}

// HW packed fp32->bf16 convert: lo = bf16(a), hi = bf16(b), RNE.
__device__ __forceinline__ unsigned cvt_pk_bf16(float a, float b) {
    unsigned r;
    asm("v_cvt_pk_bf16_f32 %0, %1, %2" : "=v"(r) : "v"(a), "v"(b));
    return r;
}

// async global->LDS, 16B per lane. LDS dest must be wave-uniform base + lane*16.
__device__ __forceinline__ void async_ld16(const void* g, void* l) {
    __builtin_amdgcn_global_load_lds(
        (const __attribute__((address_space(1))) unsigned int*)g,
        (__attribute__((address_space(3))) unsigned int*)l, 16, 0, 0);
}

// ---------------- routing: per-expert token lists ----------------
__global__ void route_kernel(const int* __restrict__ mask, const float* __restrict__ rw,
                             int* __restrict__ cnt, int* __restrict__ list,
                             float* __restrict__ wgt) {
    int t = blockIdx.x * blockDim.x + threadIdx.x;
    if (t >= NTOK) return;
#pragma unroll
    for (int e = 0; e < NEXP; ++e) {
#pragma unroll
        for (int k = 0; k < 2; ++k) {
            if (mask[(e * 2 + k) * NTOK + t] != 0) {
                int pos = atomicAdd(&cnt[e], 1);
                if (pos < CAP) {
                    list[e * CAP + pos] = t;
                    wgt[e * CAP + pos] = rw[t * 2 + k];
                }
            }
        }
    }
}

// ---------------- X: fp32 -> bf16, same layout ----------------
__global__ void xcvt_kernel(const float* __restrict__ X, u16* __restrict__ Xb) {
    const int i = (blockIdx.x * 256 + threadIdx.x) * 8;
    float4 a = *(const float4*)&X[i];
    float4 b = *(const float4*)&X[i + 4];
    float v[8] = {a.x, a.y, a.z, a.w, b.x, b.y, b.z, b.w};
    *(shortx8*)&Xb[i] = pack8(v);
}

// ---------------- W prep (merged): [e][K][N] fp32 -> [e][N][K] bf16 for w1,w3,w2 ----------------
__global__ void transpose_cvt_all_kernel(const float* __restrict__ w1,
                                         const float* __restrict__ w2,
                                         const float* __restrict__ w3,
                                         u16* __restrict__ W1b, u16* __restrict__ W2b,
                                         u16* __restrict__ W3b) {
    const int wsel = blockIdx.z;
    const int e    = blockIdx.y;
    const float* src; u16* dst; int K, N, nx;
    if (wsel == 0)      { src = w1; dst = W1b; K = HID;   N = INTER; nx = INTER / 64; }
    else if (wsel == 1) { src = w3; dst = W3b; K = HID;   N = INTER; nx = INTER / 64; }
    else                { src = w2; dst = W2b; K = INTER; N = HID;   nx = HID / 64;   }
    src += (size_t)e * K * N;
    dst += (size_t)e * K * N;
    const int tile = blockIdx.x;
    const int n0 = (tile % nx) * 64;
    const int k0 = (tile / nx) * 64;

    __shared__ unsigned ldsT[64 * 34];   // [n][34] u32: u16 col c of row n == k0 + c; +2 u32 pad
    const int tid = threadIdx.x;
    {
        const int np = tid & 15;             // n-patch: cols n0 + np*4 .. +3
        const int kp = tid >> 4;             // 0..15:  rows k0 + kp*4 .. +3
        const float* sp = src + (size_t)(k0 + kp * 4) * N + n0 + np * 4;
        float4 r0 = *(const float4*)sp;
        float4 r1 = *(const float4*)(sp + (size_t)N);
        float4 r2 = *(const float4*)(sp + 2 * (size_t)N);
        float4 r3 = *(const float4*)(sp + 3 * (size_t)N);
        const float c0[4] = {r0.x, r0.y, r0.z, r0.w};
        const float c1[4] = {r1.x, r1.y, r1.z, r1.w};
        const float c2[4] = {r2.x, r2.y, r2.z, r2.w};
        const float c3[4] = {r3.x, r3.y, r3.z, r3.w};
#pragma unroll
        for (int j = 0; j < 4; ++j) {
            const int n = np * 4 + j;
            uint2 w;
            w.x = cvt_pk_bf16(c0[j], c1[j]);   // (k+0, k+1) of dst row n
            w.y = cvt_pk_bf16(c2[j], c3[j]);   // (k+2, k+3)
            *(uint2*)&ldsT[n * 34 + kp * 2] = w;
        }
    }
    __syncthreads();
    {
        const int n = tid >> 2;              // 0..63
        const int q = tid & 3;               // 16-k chunk
        unsigned r[8];
#pragma unroll
        for (int i = 0; i < 4; ++i) {
            uint2 v = *(const uint2*)&ldsT[n * 34 + (q * 4 + i) * 2];
            r[i * 2] = v.x; r[i * 2 + 1] = v.y;
        }
        u16* dp = dst + (size_t)(n0 + n) * K + k0 + q * 16;
        *(uint4*)&dp[0] = *(const uint4*)&r[0];
        *(uint4*)&dp[8] = *(const uint4*)&r[4];
    }
}

// ---------------- GEMM1: H = silu(X w1) * (X w3) * rw, bf16 out ----------------
// A: gathered token rows of Xb [tok][HID]; B: W1b/W3b [e][INTER][HID] (n-major).
// T2 both-sides swizzle (verified r1: conflicts 1.17e7 -> 0).
// T3/T4: depth-3 pipeline, counted vmcnt(6) in main loop (never 0), stage(t+2)
// issued right after the barrier so loads get ~2 compute phases to land.
// LDS: 3 bufs x (A+B1+B3) x 8KB = 72KB dynamic.
__global__ __launch_bounds__(256, 2)
void gemm1_kernel(const u16* __restrict__ Xb, const u16* __restrict__ W1b,
                  const u16* __restrict__ W3b, const int* __restrict__ cnt,
                  const int* __restrict__ list, const float* __restrict__ wgt,
                  u16* __restrict__ H) {
    extern __shared__ u16 sm[];          // 3 * 3 * BM * BK u16 = 72 KB
    const int e  = blockIdx.z;
    const int ce = min(cnt[e], CAP);
    const int m0 = blockIdx.y * BM;
    if (m0 >= ce) return;
    const int n0 = blockIdx.x * BN;

    const int tid  = threadIdx.x;
    const int lane = tid & 63;
    const int wave = tid >> 6;

    // staging map: chunk c in {0,1}: lds u16-off = wave*1024 + c*512 + lane*8
    //   -> row = wave*32 + c*16 + lane/4, kslot = lane&3
    const int srow0 = wave * 32 + (lane >> 2);
    const int srow1 = srow0 + 16;
    const int s0   = (srow0 >> 1) & 3;           // same for srow0/srow1
    const int scol = ((lane & 3) ^ s0) * 8;      // pre-swizzled global k-chunk
    const int lo0 = wave * 1024 + lane * 8;
    const int lo1 = lo0 + 512;

    const int t0 = list[e * CAP + min(m0 + srow0, ce - 1)];
    const int t1 = list[e * CAP + min(m0 + srow1, ce - 1)];
    const u16* ap0  = Xb + (size_t)t0 * HID + scol;
    const u16* ap1  = Xb + (size_t)t1 * HID + scol;
    const u16* b1p0 = W1b + ((size_t)e * INTER + n0 + srow0) * HID + scol;
    const u16* b1p1 = b1p0 + (size_t)16 * HID;
    const u16* b3p0 = W3b + ((size_t)e * INTER + n0 + srow0) * HID + scol;
    const u16* b3p1 = b3p0 + (size_t)16 * HID;

    const int fl = lane & 15, fq = lane >> 4;
    const int fqs = (fq ^ ((fl >> 1) & 3)) * 8;  // swizzled read slot (u16 units)
    const int wm  = (wave >> 1) * 64;
    const int wnn = (wave & 1) * 64;

    auto stage = [&](int b, int kk) {
        u16* base = sm + b * (3 * BM * BK);
        async_ld16(ap0  + kk, base + lo0);
        async_ld16(ap1  + kk, base + lo1);
        async_ld16(b1p0 + kk, base + BM * BK + lo0);
        async_ld16(b1p1 + kk, base + BM * BK + lo1);
        async_ld16(b3p0 + kk, base + 2 * BM * BK + lo0);
        async_ld16(b3p1 + kk, base + 2 * BM * BK + lo1);
    };

    floatx4 acc1[4][4], acc3[4][4];
#pragma unroll
    for (int i = 0; i < 4; ++i)
#pragma unroll
        for (int j = 0; j < 4; ++j)
#pragma unroll
            for (int r = 0; r < 4; ++r) { acc1[i][j][r] = 0.f; acc3[i][j][r] = 0.f; }

    auto compute = [&](const u16* bA) {
        const u16* bB1 = bA + BM * BK;
        const u16* bB3 = bA + 2 * BM * BK;
        shortx8 af[4], b1f[4], b3f[4];
#pragma unroll
        for (int i = 0; i < 4; ++i)
            af[i] = *(const shortx8*)&bA[(wm + i * 16 + fl) * BK + fqs];
#pragma unroll
        for (int j = 0; j < 4; ++j) {
            b1f[j] = *(const shortx8*)&bB1[(wnn + j * 16 + fl) * BK + fqs];
            b3f[j] = *(const shortx8*)&bB3[(wnn + j * 16 + fl) * BK + fqs];
        }
#pragma unroll
        for (int i = 0; i < 4; ++i)
#pragma unroll
            for (int j = 0; j < 4; ++j) {
                acc1[i][j] = __builtin_amdgcn_mfma_f32_16x16x32_bf16(af[i], b1f[j], acc1[i][j], 0, 0, 0);
                acc3[i][j] = __builtin_amdgcn_mfma_f32_16x16x32_bf16(af[i], b3f[j], acc3[i][j], 0, 0, 0);
            }
    };

    const int NT = HID / BK;   // 32
    stage(0, 0);
    stage(1, BK);

    int ct = 0;
    for (int t = 0; t < NT - 1; ++t) {
        WAITVM(6);                       // tile t landed; tile t+1 may be in flight
        __builtin_amdgcn_s_barrier();
        __builtin_amdgcn_sched_barrier(0);
        if (t + 2 < NT) {
            int sb = ct + 2; if (sb >= 3) sb -= 3;
            stage(sb, (t + 2) * BK);     // overwrites buf read at iter t-1: safe post-barrier
        }
        compute(sm + ct * (3 * BM * BK));
        ct = (ct == 2) ? 0 : ct + 1;
    }
    WAITVM(0);                           // last tile
    __builtin_amdgcn_s_barrier();
    __builtin_amdgcn_sched_barrier(0);
    compute(sm + ct * (3 * BM * BK));

    // epilogue: silu(a1)*a3 * rw -> bf16 H
#pragma unroll
    for (int i = 0; i < 4; ++i) {
        const int rowb = m0 + wm + i * 16 + fq * 4;
#pragma unroll
        for (int r = 0; r < 4; ++r) {
            const int row = rowb + r;
            const bool valid = row < ce;
            const float rwv = valid ? wgt[e * CAP + row] : 0.f;
            u16* hp = H + (size_t)(e * CAP + (valid ? row : 0)) * INTER;
#pragma unroll
            for (int j = 0; j < 4; ++j) {
                const int col = n0 + wnn + j * 16 + fl;
                float h1 = acc1[i][j][r];
                float h3 = acc3[i][j][r];
                float sv = h1 / (1.f + __expf(-h1)) * h3 * rwv;
                if (valid) hp[col] = f2bf(sv);
            }
        }
    }
}

// ---------------- GEMM2: out[tok] += H w2 ----------------
// Same depth-3 counted-vmcnt pipeline. LDS: 3 bufs x (A+B) x 8KB = 48KB static.
__global__ __launch_bounds__(256, 2)
void gemm2_kernel(const u16* __restrict__ H, const u16* __restrict__ W2b,
                  const int* __restrict__ cnt, const int* __restrict__ list,
                  float* __restrict__ out) {
    const int e  = blockIdx.z;
    const int ce = min(cnt[e], CAP);
    const int m0 = blockIdx.y * BM;
    if (m0 >= ce) return;
    const int n0 = blockIdx.x * BN;

    __shared__ u16 sm[3 * 2 * BM * BK];   // 48 KB

    const int tid  = threadIdx.x;
    const int lane = tid & 63;
    const int wave = tid >> 6;

    const int srow0 = wave * 32 + (lane >> 2);
    const int s0   = (srow0 >> 1) & 3;
    const int scol = ((lane & 3) ^ s0) * 8;
    const int lo0 = wave * 1024 + lane * 8;
    const int lo1 = lo0 + 512;

    const u16* ap0 = H + (size_t)(e * CAP + m0 + srow0) * INTER + scol;  // rows >= ce: poison, masked later
    const u16* ap1 = ap0 + (size_t)16 * INTER;
    const u16* bp0 = W2b + ((size_t)e * HID + n0 + srow0) * INTER + scol;
    const u16* bp1 = bp0 + (size_t)16 * INTER;

    const int fl = lane & 15, fq = lane >> 4;
    const int fqs = (fq ^ ((fl >> 1) & 3)) * 8;
    const int wm  = (wave >> 1) * 64;
    const int wnn = (wave & 1) * 64;

    auto stage = [&](int b, int kk) {
        u16* base = sm + b * (2 * BM * BK);
        async_ld16(ap0 + kk, base + lo0);
        async_ld16(ap1 + kk, base + lo1);
        async_ld16(bp0 + kk, base + BM * BK + lo0);
        async_ld16(bp1 + kk, base + BM * BK + lo1);
    };

    floatx4 acc[4][4];
#pragma unroll
    for (int i = 0; i < 4; ++i)
#pragma unroll
        for (int j = 0; j < 4; ++j)
#pragma unroll
            for (int r = 0; r < 4; ++r) acc[i][j][r] = 0.f;

    auto compute = [&](const u16* bA) {
        const u16* bB = bA + BM * BK;
        shortx8 af[4], bf[4];
#pragma unroll
        for (int i = 0; i < 4; ++i)
            af[i] = *(const shortx8*)&bA[(wm + i * 16 + fl) * BK + fqs];
#pragma unroll
        for (int j = 0; j < 4; ++j)
            bf[j] = *(const shortx8*)&bB[(wnn + j * 16 + fl) * BK + fqs];
#pragma unroll
        for (int i = 0; i < 4; ++i)
#pragma unroll
            for (int j = 0; j < 4; ++j)
                acc[i][j] = __builtin_amdgcn_mfma_f32_16x16x32_bf16(af[i], bf[j], acc[i][j], 0, 0, 0);
    };

    const int NT = INTER / BK;   // 112
    stage(0, 0);
    stage(1, BK);

    int ct = 0;
    for (int t = 0; t < NT - 1; ++t) {
        WAITVM(4);
        __builtin_amdgcn_s_barrier();
        __builtin_amdgcn_sched_barrier(0);
        if (t + 2 < NT) {
            int sb = ct + 2; if (sb >= 3) sb -= 3;
            stage(sb, (t + 2) * BK);
        }
        compute(sm + ct * (2 * BM * BK));
        ct = (ct == 2) ? 0 : ct + 1;
    }
    WAITVM(0);
    __builtin_amdgcn_s_barrier();
    __builtin_amdgcn_sched_barrier(0);
    compute(sm + ct * (2 * BM * BK));

#pragma unroll
    for (int i = 0; i < 4; ++i) {
        const int rowb = m0 + wm + i * 16 + fq * 4;
#pragma unroll
        for (int r = 0; r < 4; ++r) {
            const int row = rowb + r;
            const bool valid = row < ce;
            const int tok = valid ? list[e * CAP + row] : 0;
            float* op = out + (size_t)tok * HID;
#pragma unroll
            for (int j = 0; j < 4; ++j) {
                const int col = n0 + wnn + j * 16 + fl;
                if (valid) atomicAdd(&op[col], acc[i][j][r]);
            }
        }
    }
}

extern "C" void kernel_launch(void* const* d_in, const int* in_sizes, int n_in,
                              void* d_out, int out_size, void* d_ws, size_t ws_size,
                              hipStream_t stream) {
    const int*   mask = (const int*)  d_in[0];
    const float* X    = (const float*)d_in[1];
    const float* rw   = (const float*)d_in[2];
    const float* w1   = (const float*)d_in[3];
    const float* w2   = (const float*)d_in[4];
    const float* w3   = (const float*)d_in[5];
    float* out = (float*)d_out;

    char* ws = (char*)d_ws;
    size_t off = 0;
    int*   cnt  = (int*)(ws + off);  off += 256;
    int*   list = (int*)(ws + off);  off += (size_t)NEXP * CAP * 4;      // 64 KB
    float* wgt  = (float*)(ws + off); off += (size_t)NEXP * CAP * 4;     // 64 KB
    u16*   Xb   = (u16*)(ws + off);  off += (size_t)NTOK * HID * 2;      // 8 MB
    u16*   W1b  = (u16*)(ws + off);  off += (size_t)NEXP * HID * INTER * 2;  // 56 MB
    u16*   W3b  = (u16*)(ws + off);  off += (size_t)NEXP * HID * INTER * 2;  // 56 MB
    u16*   W2b  = (u16*)(ws + off);  off += (size_t)NEXP * HID * INTER * 2;  // 56 MB
    u16*   H    = (u16*)(ws + off);  off += (size_t)NEXP * CAP * INTER * 2;  // 112 MB

    // allow 72KB dynamic LDS for gemm1 (immediate call, not a stream op -> graph-safe)
    static bool attr_done = false;
    if (!attr_done) {
        (void)hipFuncSetAttribute((const void*)gemm1_kernel,
                                  hipFuncAttributeMaxDynamicSharedMemorySize, 73728);
        attr_done = true;
    }

    hipMemsetAsync(cnt, 0, 256, stream);
    hipMemsetAsync(d_out, 0, (size_t)out_size * sizeof(float), stream);

    route_kernel<<<dim3((NTOK + 255) / 256), dim3(256), 0, stream>>>(mask, rw, cnt, list, wgt);
    xcvt_kernel<<<dim3(NTOK * HID / (256 * 8)), dim3(256), 0, stream>>>(X, Xb);
    transpose_cvt_all_kernel<<<dim3((HID / 64) * (INTER / 64), NEXP, 3), dim3(256), 0, stream>>>(
        w1, w2, w3, W1b, W2b, W3b);

    gemm1_kernel<<<dim3(INTER / BN, CAP / BM, NEXP), dim3(256), 73728, stream>>>(Xb, W1b, W3b, cnt, list, wgt, H);
    gemm2_kernel<<<dim3(HID / BN, CAP / BM, NEXP), dim3(256), 0, stream>>>(H, W2b, cnt, list, out);
}